// Round 9
// baseline (655.724 us; speedup 1.0000x reference)
//
#include <hip/hip_runtime.h>
#include <hip/hip_bf16.h>
#include <hip/hip_cooperative_groups.h>

namespace cg = cooperative_groups;

// Problem constants (B=2,S=2048 -> T=4096 tokens), H=1024, F=512, E=8, top-2.
#define T_TOK    4096
#define H_DIM    1024
#define F_DIM    512
#define N_EXP    8
#define N_ASSIGN 8192          // T_TOK * 2
#define BM 128
#define BN 128
#define BK 64
#define MAX_TILES 80
#define GRID_MT   71           // worst-case sum_e ceil(Ne/128) = 64 + 7
#define COOP_GRID 512          // 2 blocks/CU co-residency demand (R8 failed at 568: runtime
                               // occupancy validation; 512 = weakest useful ask). lb(256,2).
// Phase-A unit enumeration: 4096 gate/up transpose units + 2048 down units + 1024 routing units
#define TRU_GU   4096
#define TRU_ALL  6144
#define UNITS_A  (TRU_ALL + 1024)
#define TR_BLOCKS (32 * 16 * 24)   // fallback transpose grid

typedef __bf16 bf16x8 __attribute__((ext_vector_type(8)));
typedef __bf16 bf16x2 __attribute__((ext_vector_type(2)));
typedef float  f32x4  __attribute__((ext_vector_type(4)));

#define MFMA16(a, b, c) __builtin_amdgcn_mfma_f32_16x16x32_bf16((a), (b), (c), 0, 0, 0)

__device__ __forceinline__ void gl_lds16(const __bf16* g, __bf16* l) {
    __builtin_amdgcn_global_load_lds(
        (const __attribute__((address_space(1))) unsigned int*)g,
        (__attribute__((address_space(3))) unsigned int*)l,
        16, 0, 0);
}

// ===========================================================================
// Cooperative mega-kernel (one launch, grid.sync between phases).
// ===========================================================================
__global__ __launch_bounds__(256, 2) void moe_fused(
    const float* __restrict__ x,  const float* __restrict__ Wr,
    const float* __restrict__ Wg, const float* __restrict__ Wu, const float* __restrict__ Wd,
    __bf16* __restrict__ xb, int* __restrict__ top_e, float* __restrict__ top_w,
    __bf16* __restrict__ Wcat, __bf16* __restrict__ Wdt,
    int* __restrict__ perm, float* __restrict__ wts, int* __restrict__ tokslot,
    __bf16* __restrict__ act, __bf16* __restrict__ P, float* __restrict__ out,
    int* __restrict__ tile_e, int* __restrict__ tile_m0, int* __restrict__ tile_cnt,
    int* __restrict__ n_tiles)
{
    cg::grid_group grid = cg::this_grid();
    __shared__ __align__(16) char smem[34304];
    int tid = threadIdx.x;
    int wave = tid >> 6, lane = tid & 63;

    // ============================ Phase A: prep ============================
    {
        float (*tile)[33] = (float(*)[33])smem;   // 64 x 33 fp32 = 8448 B
        for (int u = blockIdx.x; u < UNITS_A; u += COOP_GRID) {
            if (u < TRU_ALL) {
                const float* src; int C, z, c0, r0;
                if (u < TRU_GU) {            // Wg/Wu: R=1024, C=512
                    z = u >> 8; int rem = u & 255;
                    c0 = (rem & 15) * 32; r0 = (rem >> 4) * 64;
                    src = ((z < 8) ? Wg + (size_t)z * H_DIM * F_DIM
                                   : Wu + (size_t)(z - 8) * H_DIM * F_DIM);
                    C = F_DIM;
                } else {                     // Wd: R=512, C=1024
                    int v = u - TRU_GU; z = 16 + (v >> 8); int rem = v & 255;
                    c0 = (rem & 31) * 32; r0 = (rem >> 5) * 64;
                    src = Wd + (size_t)(z - 16) * F_DIM * H_DIM;
                    C = H_DIM;
                }
                int tx = tid & 31, ty = tid >> 5;     // 32 x 8
#pragma unroll
                for (int i = 0; i < 8; ++i)
                    tile[ty + 8 * i][tx] = src[(size_t)(r0 + ty + 8 * i) * C + c0 + tx];
                __syncthreads();
                if (z < 16) {
                    int e = (z < 8) ? z : z - 8;
                    int sel = (z < 8) ? 0 : 16;
                    __bf16* dst = Wcat + (size_t)e * (2 * F_DIM) * H_DIM;
#pragma unroll
                    for (int i = 0; i < 4; ++i) {
                        int f = c0 + ty + 8 * i;
                        int p = ((f >> 4) << 5) + (f & 15) + sel;
                        bf16x2 v = { (__bf16)tile[2 * tx][ty + 8 * i], (__bf16)tile[2 * tx + 1][ty + 8 * i] };
                        *(bf16x2*)&dst[(size_t)p * H_DIM + r0 + 2 * tx] = v;
                    }
                } else {
                    __bf16* dst = Wdt + (size_t)(z - 16) * H_DIM * F_DIM;
#pragma unroll
                    for (int i = 0; i < 4; ++i) {
                        bf16x2 v = { (__bf16)tile[2 * tx][ty + 8 * i], (__bf16)tile[2 * tx + 1][ty + 8 * i] };
                        *(bf16x2*)&dst[(size_t)(c0 + ty + 8 * i) * F_DIM + r0 + 2 * tx] = v;
                    }
                }
                __syncthreads();
            } else {
                // routing: 4 tokens, 1 wave each
                int t = (u - TRU_ALL) * 4 + wave;
                const float* xrow = x + (size_t)t * H_DIM;
                __bf16* xbrow = xb + (size_t)t * H_DIM;
                float part[N_EXP];
#pragma unroll
                for (int e = 0; e < N_EXP; ++e) part[e] = 0.f;
#pragma unroll
                for (int half = 0; half < 2; ++half) {
                    int h0 = half * 512 + lane * 8;
                    float4 v0 = *(const float4*)(xrow + h0);
                    float4 v1 = *(const float4*)(xrow + h0 + 4);
                    float xs[8] = {v0.x, v0.y, v0.z, v0.w, v1.x, v1.y, v1.z, v1.w};
                    bf16x8 bv;
#pragma unroll
                    for (int i = 0; i < 8; ++i) bv[i] = (__bf16)xs[i];
                    *(bf16x8*)(xbrow + h0) = bv;
#pragma unroll
                    for (int i = 0; i < 8; ++i) {
                        const float4* wr = (const float4*)(Wr + (size_t)(h0 + i) * N_EXP);
                        float4 w0 = wr[0], w1 = wr[1];
                        part[0] += xs[i] * w0.x; part[1] += xs[i] * w0.y;
                        part[2] += xs[i] * w0.z; part[3] += xs[i] * w0.w;
                        part[4] += xs[i] * w1.x; part[5] += xs[i] * w1.y;
                        part[6] += xs[i] * w1.z; part[7] += xs[i] * w1.w;
                    }
                }
#pragma unroll
                for (int m = 1; m < 64; m <<= 1) {
#pragma unroll
                    for (int e = 0; e < N_EXP; ++e) part[e] += __shfl_xor(part[e], m, 64);
                }
                if (lane == 0) {
                    float v1 = -1e30f, v2 = -1e30f;
                    int i1 = 0, i2 = 0;
#pragma unroll
                    for (int e = 0; e < N_EXP; ++e) {
                        float p = part[e];
                        if (p > v1)      { v2 = v1; i2 = i1; v1 = p; i1 = e; }
                        else if (p > v2) { v2 = p;  i2 = e; }
                    }
                    float w1 = 1.f / (1.f + __expf(v2 - v1));
                    top_e[t * 2]     = i1;  top_e[t * 2 + 1] = i2;
                    top_w[t * 2]     = w1;  top_w[t * 2 + 1] = 1.f - w1;
                }
            }
        }
    }
    __threadfence();
    grid.sync();

    // ============================ Phase B: sort ============================
    if (blockIdx.x < N_EXP) {
        int (*hist)[256] = (int(*)[256])smem;           // 8 KB
        int* ebase = (int*)(smem + 8192);
        int myexp = blockIdx.x;
        int c[N_EXP];
#pragma unroll
        for (int e = 0; e < N_EXP; ++e) c[e] = 0;
#pragma unroll 4
        for (int i = 0; i < 32; ++i) {
            int ee = top_e[tid * 32 + i];
#pragma unroll
            for (int e = 0; e < N_EXP; ++e) c[e] += (ee == e);
        }
#pragma unroll
        for (int e = 0; e < N_EXP; ++e) hist[e][tid] = c[e];
        __syncthreads();
        for (int s = 1; s < 256; s <<= 1) {
            int v[N_EXP];
#pragma unroll
            for (int e = 0; e < N_EXP; ++e) v[e] = (tid >= s) ? hist[e][tid - s] : 0;
            __syncthreads();
#pragma unroll
            for (int e = 0; e < N_EXP; ++e) hist[e][tid] += v[e];
            __syncthreads();
        }
        if (tid == 0) {
            int o = 0, nt = 0;
            for (int e = 0; e < N_EXP; ++e) {
                ebase[e] = o;
                int ne = hist[e][255];
                if (myexp == 0) {
                    for (int m0 = 0; m0 < ne; m0 += BM) {
                        tile_e[nt]   = e;
                        tile_m0[nt]  = o + m0;
                        tile_cnt[nt] = (ne - m0 < BM) ? (ne - m0) : BM;
                        ++nt;
                    }
                }
                o += ne;
            }
            if (myexp == 0) *n_tiles = nt;
        }
        __syncthreads();
        int base = ebase[myexp] + hist[myexp][tid] - c[myexp];
#pragma unroll 4
        for (int i = 0; i < 32; ++i) {
            int a = tid * 32 + i;
            if (top_e[a] == myexp) {
                perm[base]   = a >> 1;
                wts[base]    = top_w[a];
                tokslot[a]   = base;
                ++base;
            }
        }
    }
    __threadfence();
    grid.sync();

    int nt = *n_tiles;
    int quad = lane >> 4, l16 = lane & 15;
    int wm = wave & 1, wn = wave >> 1;
    int srow   = wave * 8 + (lane >> 3);
    int schunk = (((lane & 7) ^ ((lane >> 3) & 7))) * 8;   // XOR swizzle (global side)
    __bf16* As = (__bf16*)smem;                 // 16 KB
    __bf16* Bs = (__bf16*)(smem + 16384);       // 16 KB
    int*    rowtok = (int*)(smem + 32768);      // 512 B
    float*  roww   = (float*)(smem + 33280);    // 512 B
    __bf16* aLds = As + wave * 512;
    __bf16* bLds = Bs + wave * 512;

    // ============================ Phase C: gateup ==========================
    for (int jj = blockIdx.x; jj < nt * 8; jj += COOP_GRID) {
        int mt = jj >> 3;
        int e = tile_e[mt], m0 = tile_m0[mt], mcnt = tile_cnt[mt];
        int n0 = (jj & 7) * BN;
        __syncthreads();     // protect prev job's roww/As reads before overwrite
        if (tid < BM) {
            int slot = m0 + ((tid < mcnt) ? tid : 0);
            rowtok[tid] = perm[slot];
            roww[tid]   = wts[slot];
        }
        __syncthreads();
        const __bf16* We = Wcat + (size_t)e * (2 * F_DIM) * H_DIM;
        const __bf16* aptr[4];
        const __bf16* bptr[4];
#pragma unroll
        for (int j = 0; j < 4; ++j) {
            int r = j * 32 + srow;
            aptr[j] = xb + (size_t)rowtok[r] * H_DIM + schunk;
            bptr[j] = We + (size_t)(n0 + r) * H_DIM + schunk;
        }
        f32x4 acc[4][4];
#pragma unroll
        for (int a = 0; a < 4; ++a)
#pragma unroll
            for (int b = 0; b < 4; ++b) acc[a][b] = (f32x4){0.f, 0.f, 0.f, 0.f};

        for (int k0 = 0; k0 < H_DIM; k0 += BK) {
#pragma unroll
            for (int j = 0; j < 4; ++j) {
                gl_lds16(aptr[j] + k0, aLds + j * 2048);
                gl_lds16(bptr[j] + k0, bLds + j * 2048);
            }
            __syncthreads();
#pragma unroll
            for (int s = 0; s < 2; ++s) {
                int sw = (((quad + s * 4) ^ (l16 & 7))) * 8;
                bf16x8 af[4], bf[4];
#pragma unroll
                for (int im = 0; im < 4; ++im)
                    af[im] = *(const bf16x8*)&As[(wm * 64 + im * 16 + l16) * 64 + sw];
#pragma unroll
                for (int in = 0; in < 4; ++in)
                    bf[in] = *(const bf16x8*)&Bs[(wn * 64 + in * 16 + l16) * 64 + sw];
#pragma unroll
                for (int im = 0; im < 4; ++im)
#pragma unroll
                    for (int in = 0; in < 4; ++in)
                        acc[im][in] = MFMA16(af[im], bf[in], acc[im][in]);
            }
            __syncthreads();
        }
        int fbase = (n0 >> 1) + wn * 32;
#pragma unroll
        for (int im = 0; im < 4; ++im) {
#pragma unroll
            for (int ip = 0; ip < 2; ++ip) {
                f32x4 g = acc[im][ip * 2], u = acc[im][ip * 2 + 1];
                int fcol = fbase + ip * 16 + l16;
#pragma unroll
                for (int r = 0; r < 4; ++r) {
                    int rl = wm * 64 + im * 16 + quad * 4 + r;
                    if (rl < mcnt) {
                        float gv = g[r], uv = u[r];
                        float sg = gv / (1.f + __expf(-gv));
                        act[(size_t)(m0 + rl) * F_DIM + fcol] = (__bf16)(sg * uv * roww[rl]);
                    }
                }
            }
        }
    }
    __threadfence();
    grid.sync();

    // ============================ Phase D: down ============================
    for (int jj = blockIdx.x; jj < nt * 8; jj += COOP_GRID) {
        int mt = jj >> 3;
        int e = tile_e[mt], m0 = tile_m0[mt], mcnt = tile_cnt[mt];
        int n0 = (jj & 7) * BN;
        const __bf16* Wd_e = Wdt + (size_t)e * H_DIM * F_DIM;
        const __bf16* aptr[4];
        const __bf16* bptr[4];
#pragma unroll
        for (int j = 0; j < 4; ++j) {
            int r = j * 32 + srow;
            int ar = m0 + ((r < mcnt) ? r : 0);
            aptr[j] = act  + (size_t)ar * F_DIM + schunk;
            bptr[j] = Wd_e + (size_t)(n0 + r) * F_DIM + schunk;
        }
        f32x4 acc[4][4];
#pragma unroll
        for (int a = 0; a < 4; ++a)
#pragma unroll
            for (int b = 0; b < 4; ++b) acc[a][b] = (f32x4){0.f, 0.f, 0.f, 0.f};

        for (int k0 = 0; k0 < F_DIM; k0 += BK) {
#pragma unroll
            for (int j = 0; j < 4; ++j) {
                gl_lds16(aptr[j] + k0, aLds + j * 2048);
                gl_lds16(bptr[j] + k0, bLds + j * 2048);
            }
            __syncthreads();
#pragma unroll
            for (int s = 0; s < 2; ++s) {
                int sw = (((quad + s * 4) ^ (l16 & 7))) * 8;
                bf16x8 af[4], bf[4];
#pragma unroll
                for (int im = 0; im < 4; ++im)
                    af[im] = *(const bf16x8*)&As[(wm * 64 + im * 16 + l16) * 64 + sw];
#pragma unroll
                for (int in = 0; in < 4; ++in)
                    bf[in] = *(const bf16x8*)&Bs[(wn * 64 + in * 16 + l16) * 64 + sw];
#pragma unroll
                for (int im = 0; im < 4; ++im)
#pragma unroll
                    for (int in = 0; in < 4; ++in)
                        acc[im][in] = MFMA16(af[im], bf[in], acc[im][in]);
            }
            __syncthreads();
        }
#pragma unroll
        for (int im = 0; im < 4; ++im) {
#pragma unroll
            for (int in = 0; in < 4; ++in) {
                int col = n0 + wn * 64 + in * 16 + l16;
#pragma unroll
                for (int r = 0; r < 4; ++r) {
                    int rl = wm * 64 + im * 16 + quad * 4 + r;
                    if (rl < mcnt)
                        P[(size_t)(m0 + rl) * H_DIM + col] = (__bf16)acc[im][in][r];
                }
            }
        }
    }
    __threadfence();
    grid.sync();

    // ============================ Phase E: combine =========================
    for (int u = blockIdx.x; u < T_TOK / 4; u += COOP_GRID) {
        int t = u * 4 + wave;
        int s1 = tokslot[2 * t], s2 = tokslot[2 * t + 1];
        const bf16x8* p1 = (const bf16x8*)(P + (size_t)s1 * H_DIM);
        const bf16x8* p2 = (const bf16x8*)(P + (size_t)s2 * H_DIM);
        float* o = out + (size_t)t * H_DIM;
#pragma unroll
        for (int i = 0; i < 2; ++i) {
            int idx = i * 64 + lane;
            bf16x8 a = p1[idx], b = p2[idx];
            f32x4 lo, hi;
#pragma unroll
            for (int j = 0; j < 4; ++j) lo[j] = (float)a[j] + (float)b[j];
#pragma unroll
            for (int j = 0; j < 4; ++j) hi[j] = (float)a[4 + j] + (float)b[4 + j];
            *(f32x4*)(o + idx * 8)     = lo;
            *(f32x4*)(o + idx * 8 + 4) = hi;
        }
    }
}

// ===========================================================================
// Fallback pipeline (R7, proven 206us PASS) -- used if cooperative launch is
// rejected by the runtime.
// ===========================================================================
__global__ __launch_bounds__(256) void prep_kernel(
    const float* __restrict__ x,  const float* __restrict__ Wr,
    const float* __restrict__ Wg, const float* __restrict__ Wu, const float* __restrict__ Wd,
    __bf16* __restrict__ xb, int* __restrict__ top_e, float* __restrict__ top_w,
    __bf16* __restrict__ Wcat, __bf16* __restrict__ Wdt)
{
    __shared__ float tile[64][33];
    int b = blockIdx.x;
    if (b < TR_BLOCKS) {
        int z = b >> 9, rem = b & 511;
        int c0 = (rem & 31) * 32, r0 = (rem >> 5) * 64;
        const float* src; int R, C;
        if (z < 8)       { src = Wg + (size_t)z * H_DIM * F_DIM;        R = H_DIM; C = F_DIM; }
        else if (z < 16) { src = Wu + (size_t)(z - 8) * H_DIM * F_DIM;  R = H_DIM; C = F_DIM; }
        else             { src = Wd + (size_t)(z - 16) * F_DIM * H_DIM; R = F_DIM; C = H_DIM; }
        if (c0 >= C || r0 >= R) return;
        int tx = threadIdx.x & 31, ty = threadIdx.x >> 5;
#pragma unroll
        for (int i = 0; i < 8; ++i)
            tile[ty + 8 * i][tx] = src[(size_t)(r0 + ty + 8 * i) * C + c0 + tx];
        __syncthreads();
        if (z < 16) {
            int e = (z < 8) ? z : z - 8;
            int sel = (z < 8) ? 0 : 16;
            __bf16* dst = Wcat + (size_t)e * (2 * F_DIM) * H_DIM;
#pragma unroll
            for (int i = 0; i < 4; ++i) {
                int f = c0 + ty + 8 * i;
                int p = ((f >> 4) << 5) + (f & 15) + sel;
                bf16x2 v = { (__bf16)tile[2 * tx][ty + 8 * i], (__bf16)tile[2 * tx + 1][ty + 8 * i] };
                *(bf16x2*)&dst[(size_t)p * H_DIM + r0 + 2 * tx] = v;
            }
        } else {
            __bf16* dst = Wdt + (size_t)(z - 16) * H_DIM * F_DIM;
#pragma unroll
            for (int i = 0; i < 4; ++i) {
                bf16x2 v = { (__bf16)tile[2 * tx][ty + 8 * i], (__bf16)tile[2 * tx + 1][ty + 8 * i] };
                *(bf16x2*)&dst[(size_t)(c0 + ty + 8 * i) * F_DIM + r0 + 2 * tx] = v;
            }
        }
        return;
    }
    int wave = threadIdx.x >> 6, lane = threadIdx.x & 63;
    int t = (b - TR_BLOCKS) * 4 + wave;
    const float* xrow = x + (size_t)t * H_DIM;
    __bf16* xbrow = xb + (size_t)t * H_DIM;
    float part[N_EXP];
#pragma unroll
    for (int e = 0; e < N_EXP; ++e) part[e] = 0.f;
#pragma unroll
    for (int half = 0; half < 2; ++half) {
        int h0 = half * 512 + lane * 8;
        float4 v0 = *(const float4*)(xrow + h0);
        float4 v1 = *(const float4*)(xrow + h0 + 4);
        float xs[8] = {v0.x, v0.y, v0.z, v0.w, v1.x, v1.y, v1.z, v1.w};
        bf16x8 bv;
#pragma unroll
        for (int i = 0; i < 8; ++i) bv[i] = (__bf16)xs[i];
        *(bf16x8*)(xbrow + h0) = bv;
#pragma unroll
        for (int i = 0; i < 8; ++i) {
            const float4* wr = (const float4*)(Wr + (size_t)(h0 + i) * N_EXP);
            float4 w0 = wr[0], w1 = wr[1];
            part[0] += xs[i] * w0.x; part[1] += xs[i] * w0.y;
            part[2] += xs[i] * w0.z; part[3] += xs[i] * w0.w;
            part[4] += xs[i] * w1.x; part[5] += xs[i] * w1.y;
            part[6] += xs[i] * w1.z; part[7] += xs[i] * w1.w;
        }
    }
#pragma unroll
    for (int m = 1; m < 64; m <<= 1) {
#pragma unroll
        for (int e = 0; e < N_EXP; ++e) part[e] += __shfl_xor(part[e], m, 64);
    }
    if (lane == 0) {
        float v1 = -1e30f, v2 = -1e30f;
        int i1 = 0, i2 = 0;
#pragma unroll
        for (int e = 0; e < N_EXP; ++e) {
            float p = part[e];
            if (p > v1)      { v2 = v1; i2 = i1; v1 = p; i1 = e; }
            else if (p > v2) { v2 = p;  i2 = e; }
        }
        float w1 = 1.f / (1.f + __expf(v2 - v1));
        top_e[t * 2]     = i1;  top_e[t * 2 + 1] = i2;
        top_w[t * 2]     = w1;  top_w[t * 2 + 1] = 1.f - w1;
    }
}

__global__ __launch_bounds__(256) void sort_kernel(
    const int* __restrict__ top_e, const float* __restrict__ top_w,
    int* __restrict__ perm, float* __restrict__ wts, int* __restrict__ tokslot,
    int* __restrict__ tile_e, int* __restrict__ tile_m0, int* __restrict__ tile_cnt,
    int* __restrict__ n_tiles)
{
    __shared__ int hist[N_EXP][256];
    __shared__ int ebase[N_EXP];
    int tid = threadIdx.x, myexp = blockIdx.x;
    int c[N_EXP];
#pragma unroll
    for (int e = 0; e < N_EXP; ++e) c[e] = 0;
#pragma unroll 4
    for (int i = 0; i < 32; ++i) {
        int ee = top_e[tid * 32 + i];
#pragma unroll
        for (int e = 0; e < N_EXP; ++e) c[e] += (ee == e);
    }
#pragma unroll
    for (int e = 0; e < N_EXP; ++e) hist[e][tid] = c[e];
    __syncthreads();
    for (int s = 1; s < 256; s <<= 1) {
        int v[N_EXP];
#pragma unroll
        for (int e = 0; e < N_EXP; ++e) v[e] = (tid >= s) ? hist[e][tid - s] : 0;
        __syncthreads();
#pragma unroll
        for (int e = 0; e < N_EXP; ++e) hist[e][tid] += v[e];
        __syncthreads();
    }
    if (tid == 0) {
        int o = 0, nt = 0;
        for (int e = 0; e < N_EXP; ++e) {
            ebase[e] = o;
            int ne = hist[e][255];
            if (myexp == 0) {
                for (int m0 = 0; m0 < ne; m0 += BM) {
                    tile_e[nt]   = e;
                    tile_m0[nt]  = o + m0;
                    tile_cnt[nt] = (ne - m0 < BM) ? (ne - m0) : BM;
                    ++nt;
                }
            }
            o += ne;
        }
        if (myexp == 0) *n_tiles = nt;
    }
    __syncthreads();
    int base = ebase[myexp] + hist[myexp][tid] - c[myexp];
#pragma unroll 4
    for (int i = 0; i < 32; ++i) {
        int a = tid * 32 + i;
        if (top_e[a] == myexp) {
            perm[base]   = a >> 1;
            wts[base]    = top_w[a];
            tokslot[a]   = base;
            ++base;
        }
    }
}

__global__ __launch_bounds__(256, 3) void gateup_kernel(
    const __bf16* __restrict__ xb, const __bf16* __restrict__ Wcat,
    const int* __restrict__ perm, const float* __restrict__ wts,
    const int* __restrict__ tile_e, const int* __restrict__ tile_m0, const int* __restrict__ tile_cnt,
    const int* __restrict__ n_tiles, __bf16* __restrict__ act)
{
    int mt = blockIdx.x >> 3;
    if (mt >= *n_tiles) return;
    int e = tile_e[mt], m0 = tile_m0[mt], mcnt = tile_cnt[mt];
    int n0 = (blockIdx.x & 7) * BN;
    __shared__ __align__(16) __bf16 As[BM * BK];
    __shared__ __align__(16) __bf16 Bs[BN * BK];
    __shared__ int   rowtok[BM];
    __shared__ float roww[BM];
    int tid = threadIdx.x;
    if (tid < BM) {
        int slot = m0 + ((tid < mcnt) ? tid : 0);
        rowtok[tid] = perm[slot];
        roww[tid]   = wts[slot];
    }
    __syncthreads();
    int wave = tid >> 6, lane = tid & 63;
    int srow   = wave * 8 + (lane >> 3);
    int schunk = (((lane & 7) ^ ((lane >> 3) & 7))) * 8;
    const __bf16* We = Wcat + (size_t)e * (2 * F_DIM) * H_DIM;
    const __bf16* aptr[4];
    const __bf16* bptr[4];
#pragma unroll
    for (int j = 0; j < 4; ++j) {
        int r = j * 32 + srow;
        aptr[j] = xb + (size_t)rowtok[r] * H_DIM + schunk;
        bptr[j] = We + (size_t)(n0 + r) * H_DIM + schunk;
    }
    __bf16* aLds = As + wave * 512;
    __bf16* bLds = Bs + wave * 512;
    int wm = wave & 1, wn = wave >> 1;
    int quad = lane >> 4, l16 = lane & 15;
    f32x4 acc[4][4];
#pragma unroll
    for (int a = 0; a < 4; ++a)
#pragma unroll
        for (int b = 0; b < 4; ++b) acc[a][b] = (f32x4){0.f, 0.f, 0.f, 0.f};
    for (int k0 = 0; k0 < H_DIM; k0 += BK) {
#pragma unroll
        for (int j = 0; j < 4; ++j) {
            gl_lds16(aptr[j] + k0, aLds + j * 2048);
            gl_lds16(bptr[j] + k0, bLds + j * 2048);
        }
        __syncthreads();
#pragma unroll
        for (int s = 0; s < 2; ++s) {
            int sw = (((quad + s * 4) ^ (l16 & 7))) * 8;
            bf16x8 af[4], bf[4];
#pragma unroll
            for (int im = 0; im < 4; ++im)
                af[im] = *(const bf16x8*)&As[(wm * 64 + im * 16 + l16) * 64 + sw];
#pragma unroll
            for (int in = 0; in < 4; ++in)
                bf[in] = *(const bf16x8*)&Bs[(wn * 64 + in * 16 + l16) * 64 + sw];
#pragma unroll
            for (int im = 0; im < 4; ++im)
#pragma unroll
                for (int in = 0; in < 4; ++in)
                    acc[im][in] = MFMA16(af[im], bf[in], acc[im][in]);
        }
        __syncthreads();
    }
    int fbase = (n0 >> 1) + wn * 32;
#pragma unroll
    for (int im = 0; im < 4; ++im) {
#pragma unroll
        for (int ip = 0; ip < 2; ++ip) {
            f32x4 g = acc[im][ip * 2], u = acc[im][ip * 2 + 1];
            int fcol = fbase + ip * 16 + l16;
#pragma unroll
            for (int r = 0; r < 4; ++r) {
                int rl = wm * 64 + im * 16 + quad * 4 + r;
                if (rl < mcnt) {
                    float gv = g[r], uv = u[r];
                    float sg = gv / (1.f + __expf(-gv));
                    act[(size_t)(m0 + rl) * F_DIM + fcol] = (__bf16)(sg * uv * roww[rl]);
                }
            }
        }
    }
}

__global__ __launch_bounds__(256, 3) void down_kernel(
    const __bf16* __restrict__ act, const __bf16* __restrict__ Wdt,
    const int* __restrict__ tile_e, const int* __restrict__ tile_m0, const int* __restrict__ tile_cnt,
    const int* __restrict__ n_tiles, __bf16* __restrict__ P)
{
    int mt = blockIdx.x >> 3;
    if (mt >= *n_tiles) return;
    int e = tile_e[mt], m0 = tile_m0[mt], mcnt = tile_cnt[mt];
    int n0 = (blockIdx.x & 7) * BN;
    __shared__ __align__(16) __bf16 As[BM * BK];
    __shared__ __align__(16) __bf16 Bs[BN * BK];
    int tid = threadIdx.x;
    int wave = tid >> 6, lane = tid & 63;
    int srow   = wave * 8 + (lane >> 3);
    int schunk = (((lane & 7) ^ ((lane >> 3) & 7))) * 8;
    const __bf16* Wd_e = Wdt + (size_t)e * H_DIM * F_DIM;
    const __bf16* aptr[4];
    const __bf16* bptr[4];
#pragma unroll
    for (int j = 0; j < 4; ++j) {
        int r = j * 32 + srow;
        int ar = m0 + ((r < mcnt) ? r : 0);
        aptr[j] = act  + (size_t)ar * F_DIM + schunk;
        bptr[j] = Wd_e + (size_t)(n0 + r) * F_DIM + schunk;
    }
    __bf16* aLds = As + wave * 512;
    __bf16* bLds = Bs + wave * 512;
    int wm = wave & 1, wn = wave >> 1;
    int quad = lane >> 4, l16 = lane & 15;
    f32x4 acc[4][4];
#pragma unroll
    for (int a = 0; a < 4; ++a)
#pragma unroll
        for (int b = 0; b < 4; ++b) acc[a][b] = (f32x4){0.f, 0.f, 0.f, 0.f};
    for (int k0 = 0; k0 < F_DIM; k0 += BK) {
#pragma unroll
        for (int j = 0; j < 4; ++j) {
            gl_lds16(aptr[j] + k0, aLds + j * 2048);
            gl_lds16(bptr[j] + k0, bLds + j * 2048);
        }
        __syncthreads();
#pragma unroll
        for (int s = 0; s < 2; ++s) {
            int sw = (((quad + s * 4) ^ (l16 & 7))) * 8;
            bf16x8 af[4], bf[4];
#pragma unroll
            for (int im = 0; im < 4; ++im)
                af[im] = *(const bf16x8*)&As[(wm * 64 + im * 16 + l16) * 64 + sw];
#pragma unroll
            for (int in = 0; in < 4; ++in)
                bf[in] = *(const bf16x8*)&Bs[(wn * 64 + in * 16 + l16) * 64 + sw];
#pragma unroll
            for (int im = 0; im < 4; ++im)
#pragma unroll
                for (int in = 0; in < 4; ++in)
                    acc[im][in] = MFMA16(af[im], bf[in], acc[im][in]);
        }
        __syncthreads();
    }
#pragma unroll
    for (int im = 0; im < 4; ++im) {
#pragma unroll
        for (int in = 0; in < 4; ++in) {
            int col = n0 + wn * 64 + in * 16 + l16;
#pragma unroll
            for (int r = 0; r < 4; ++r) {
                int rl = wm * 64 + im * 16 + quad * 4 + r;
                if (rl < mcnt)
                    P[(size_t)(m0 + rl) * H_DIM + col] = (__bf16)acc[im][in][r];
            }
        }
    }
}

__global__ __launch_bounds__(256) void combine_kernel(
    const __bf16* __restrict__ P, const int* __restrict__ tokslot,
    float* __restrict__ out)
{
    int wave = threadIdx.x >> 6, lane = threadIdx.x & 63;
    int t = blockIdx.x * 4 + wave;
    int s1 = tokslot[2 * t], s2 = tokslot[2 * t + 1];
    const bf16x8* p1 = (const bf16x8*)(P + (size_t)s1 * H_DIM);
    const bf16x8* p2 = (const bf16x8*)(P + (size_t)s2 * H_DIM);
    float* o = out + (size_t)t * H_DIM;
#pragma unroll
    for (int i = 0; i < 2; ++i) {
        int idx = i * 64 + lane;
        bf16x8 a = p1[idx], b = p2[idx];
        f32x4 lo, hi;
#pragma unroll
        for (int j = 0; j < 4; ++j) lo[j] = (float)a[j] + (float)b[j];
#pragma unroll
        for (int j = 0; j < 4; ++j) hi[j] = (float)a[4 + j] + (float)b[4 + j];
        *(f32x4*)(o + idx * 8)     = lo;
        *(f32x4*)(o + idx * 8 + 4) = hi;
    }
}

// ---------------------------------------------------------------------------
extern "C" void kernel_launch(void* const* d_in, const int* in_sizes, int n_in,
                              void* d_out, int out_size, void* d_ws, size_t ws_size,
                              hipStream_t stream)
{
    const float* x  = (const float*)d_in[0];
    const float* Wr = (const float*)d_in[1];
    const float* Wg = (const float*)d_in[2];
    const float* Wu = (const float*)d_in[3];
    const float* Wd = (const float*)d_in[4];
    float* out = (float*)d_out;

    char* ws = (char*)d_ws;
    size_t off = 0;
    auto carve = [&](size_t bytes) {
        char* p = ws + off;
        off = (off + bytes + 255) & ~(size_t)255;
        return p;
    };
    __bf16* xb   = (__bf16*)carve((size_t)T_TOK * H_DIM * 2);
    __bf16* Wcat = (__bf16*)carve((size_t)N_EXP * 2 * F_DIM * H_DIM * 2);
    __bf16* Wdt  = (__bf16*)carve((size_t)N_EXP * H_DIM * F_DIM * 2);
    __bf16* act  = (__bf16*)carve((size_t)N_ASSIGN * F_DIM * 2);
    __bf16* P    = (__bf16*)carve((size_t)N_ASSIGN * H_DIM * 2);
    int*   top_e = (int*)carve((size_t)T_TOK * 2 * sizeof(int));
    float* top_w = (float*)carve((size_t)T_TOK * 2 * sizeof(float));
    int*   perm  = (int*)carve((size_t)N_ASSIGN * sizeof(int));
    float* wts   = (float*)carve((size_t)N_ASSIGN * sizeof(float));
    int*  tokslot= (int*)carve((size_t)N_ASSIGN * sizeof(int));
    int*   tl_e  = (int*)carve(MAX_TILES * sizeof(int));
    int*   tl_m0 = (int*)carve(MAX_TILES * sizeof(int));
    int*   tl_cn = (int*)carve(MAX_TILES * sizeof(int));
    int*   n_til = (int*)carve(sizeof(int));

    void* args[] = { (void*)&x, (void*)&Wr, (void*)&Wg, (void*)&Wu, (void*)&Wd,
                     (void*)&xb, (void*)&top_e, (void*)&top_w, (void*)&Wcat, (void*)&Wdt,
                     (void*)&perm, (void*)&wts, (void*)&tokslot, (void*)&act, (void*)&P,
                     (void*)&out, (void*)&tl_e, (void*)&tl_m0, (void*)&tl_cn, (void*)&n_til };
    hipError_t err = hipLaunchCooperativeKernel((void*)moe_fused, dim3(COOP_GRID), dim3(256),
                                                args, 0, stream);
    if (err != hipSuccess) {
        // Deterministic fallback: R7 five-kernel pipeline (proven PASS).
        (void)hipGetLastError();   // clear error state
        prep_kernel<<<TR_BLOCKS + T_TOK / 4, 256, 0, stream>>>(
            x, Wr, Wg, Wu, Wd, xb, top_e, top_w, Wcat, Wdt);
        sort_kernel<<<N_EXP, 256, 0, stream>>>(
            top_e, top_w, perm, wts, tokslot, tl_e, tl_m0, tl_cn, n_til);
        gateup_kernel<<<GRID_MT * 8, 256, 0, stream>>>(
            xb, Wcat, perm, wts, tl_e, tl_m0, tl_cn, n_til, act);
        down_kernel<<<GRID_MT * 8, 256, 0, stream>>>(
            act, Wdt, tl_e, tl_m0, tl_cn, n_til, P);
        combine_kernel<<<T_TOK / 4, 256, 0, stream>>>(P, tokslot, out);
    }
}

// Round 10
// 202.837 us; speedup vs baseline: 3.2328x; 3.2328x over previous
//
#include <hip/hip_runtime.h>
#include <hip/hip_bf16.h>

// Problem constants (B=2,S=2048 -> T=4096 tokens), H=1024, F=512, E=8, top-2.
#define T_TOK    4096
#define H_DIM    1024
#define F_DIM    512
#define N_EXP    8
#define N_ASSIGN 8192          // T_TOK * 2
#define BM 128
#define BN 128
#define BK 64
#define MAX_TILES 80
#define GRID_MT   71           // worst-case sum_e ceil(Ne/128) = 64 + 7
#define TRU      3072          // transpose units: 2048 (Wg/Wu) + 1024 (Wd), 64x64 tiles
#define PREP_GRID (TRU + T_TOK / 4)

typedef __bf16 bf16x8 __attribute__((ext_vector_type(8)));
typedef float  f32x4  __attribute__((ext_vector_type(4)));

#define MFMA16(a, b, c) __builtin_amdgcn_mfma_f32_16x16x32_bf16((a), (b), (c), 0, 0, 0)

// Async global->LDS, 16B per lane. LDS dest = wave-uniform base + lane*16.
__device__ __forceinline__ void gl_lds16(const __bf16* g, __bf16* l) {
    __builtin_amdgcn_global_load_lds(
        (const __attribute__((address_space(1))) unsigned int*)g,
        (__attribute__((address_space(3))) unsigned int*)l,
        16, 0, 0);
}

// ---------------------------------------------------------------------------
// prep = transpose (blocks [0,TRU)) + routing (rest).
// R9 post-mortem: coop mega-kernel was 3x SLOWER (2 blk/CU + cache flush at
// grid.sync) -- reverted to the 5-kernel pipeline. This round fixes prep's
// store side: R7 used bf16x2 (4B) stores = 8.4M store instrs at 1.4 TB/s;
// now 64x64 tiles with bf16x8 16B stores, 8 lanes = one full 128B dst row.
// LDS pad 65 -> column gather addr = 65r + c, bank = (r+c)&31; r-stride 8
// across lanes gives 2-way aliasing = free (m136).
//   z<8 : Wg[h][f] -> Wcat[e][p_g(f)][h]   p_g(f) = (f>>4)*32 + (f&15)
//   z<16: Wu[h][f] -> Wcat[e][p_u(f)][h]   p_u(f) = p_g(f) + 16
//   else: Wd[f][h] -> Wdt [e][h][f]
// Routing: 1 wave = 1 token; fused x fp32->bf16; closed-form top-2; no
// global atomics (R2: clustered atomicAdds serialized ~100us at the TCC).
// ---------------------------------------------------------------------------
__global__ __launch_bounds__(256) void prep_kernel(
    const float* __restrict__ x,  const float* __restrict__ Wr,
    const float* __restrict__ Wg, const float* __restrict__ Wu, const float* __restrict__ Wd,
    __bf16* __restrict__ xb, int* __restrict__ top_e, float* __restrict__ top_w,
    __bf16* __restrict__ Wcat, __bf16* __restrict__ Wdt)
{
    __shared__ float tile[64][65];     // 16.9 KB
    int b = blockIdx.x, tid = threadIdx.x;
    if (b < TRU) {
        // ---- transpose unit: 64 rows x 64 cols ----
        const float* src; int C, z, c0, r0;
        if (b < 2048) {                // Wg/Wu: R=1024, C=512 -> 16x8 tiles/z
            z = b >> 7; int rem = b & 127;
            c0 = (rem & 7) * 64; r0 = (rem >> 3) * 64;
            src = (z < 8) ? Wg + (size_t)z * H_DIM * F_DIM
                          : Wu + (size_t)(z - 8) * H_DIM * F_DIM;
            C = F_DIM;
        } else {                       // Wd: R=512, C=1024 -> 8x16 tiles/z
            int v = b - 2048; z = 16 + (v >> 7); int rem = v & 127;
            c0 = (rem & 15) * 64; r0 = (rem >> 4) * 64;
            src = Wd + (size_t)(z - 16) * F_DIM * H_DIM;
            C = H_DIM;
        }
        int fr = tid >> 4, f4 = tid & 15;          // 16 rows/pass, 16 float4/row
#pragma unroll
        for (int p = 0; p < 4; ++p) {
            int row = p * 16 + fr;
            float4 v = *(const float4*)(src + (size_t)(r0 + row) * C + c0 + f4 * 4);
            tile[row][f4 * 4 + 0] = v.x; tile[row][f4 * 4 + 1] = v.y;
            tile[row][f4 * 4 + 2] = v.z; tile[row][f4 * 4 + 3] = v.w;
        }
        __syncthreads();
        int j = tid & 7, cl = tid >> 3;            // chunk-of-8-rows, 32 cols/pass
#pragma unroll
        for (int p = 0; p < 2; ++p) {
            int c = cl + p * 32;
            bf16x8 v;
#pragma unroll
            for (int i = 0; i < 8; ++i) v[i] = (__bf16)tile[8 * j + i][c];
            if (z < 16) {
                int e = (z < 8) ? z : z - 8;
                int sel = (z < 8) ? 0 : 16;
                int f = c0 + c;
                int pp = ((f >> 4) << 5) + (f & 15) + sel;
                *(bf16x8*)&Wcat[(size_t)e * 2 * F_DIM * H_DIM + (size_t)pp * H_DIM + r0 + 8 * j] = v;
            } else {
                *(bf16x8*)&Wdt[(size_t)(z - 16) * H_DIM * F_DIM + (size_t)(c0 + c) * F_DIM + r0 + 8 * j] = v;
            }
        }
        return;
    }
    // ---- routing ----
    int wave = tid >> 6, lane = tid & 63;
    int t = (b - TRU) * 4 + wave;
    const float* xrow = x + (size_t)t * H_DIM;
    __bf16* xbrow = xb + (size_t)t * H_DIM;
    float part[N_EXP];
#pragma unroll
    for (int e = 0; e < N_EXP; ++e) part[e] = 0.f;
#pragma unroll
    for (int half = 0; half < 2; ++half) {
        int h0 = half * 512 + lane * 8;
        float4 v0 = *(const float4*)(xrow + h0);
        float4 v1 = *(const float4*)(xrow + h0 + 4);
        float xs[8] = {v0.x, v0.y, v0.z, v0.w, v1.x, v1.y, v1.z, v1.w};
        bf16x8 bv;
#pragma unroll
        for (int i = 0; i < 8; ++i) bv[i] = (__bf16)xs[i];
        *(bf16x8*)(xbrow + h0) = bv;
#pragma unroll
        for (int i = 0; i < 8; ++i) {
            const float4* wr = (const float4*)(Wr + (size_t)(h0 + i) * N_EXP);
            float4 w0 = wr[0], w1 = wr[1];
            part[0] += xs[i] * w0.x; part[1] += xs[i] * w0.y;
            part[2] += xs[i] * w0.z; part[3] += xs[i] * w0.w;
            part[4] += xs[i] * w1.x; part[5] += xs[i] * w1.y;
            part[6] += xs[i] * w1.z; part[7] += xs[i] * w1.w;
        }
    }
#pragma unroll
    for (int m = 1; m < 64; m <<= 1) {
#pragma unroll
        for (int e = 0; e < N_EXP; ++e) part[e] += __shfl_xor(part[e], m, 64);
    }
    if (lane == 0) {
        float v1 = -1e30f, v2 = -1e30f;
        int i1 = 0, i2 = 0;
#pragma unroll
        for (int e = 0; e < N_EXP; ++e) {
            float p = part[e];
            if (p > v1)      { v2 = v1; i2 = i1; v1 = p; i1 = e; }
            else if (p > v2) { v2 = p;  i2 = e; }
        }
        float w1 = 1.f / (1.f + __expf(v2 - v1));
        top_e[t * 2]     = i1;  top_e[t * 2 + 1] = i2;
        top_w[t * 2]     = w1;  top_w[t * 2 + 1] = 1.f - w1;
    }
}

// ---------------------------------------------------------------------------
// sort (8 blocks): each block redundantly computes histogram + scan, scatters
// ONE expert at deterministic offsets; block 0 emits tile worklist. No atomics.
// ---------------------------------------------------------------------------
__global__ __launch_bounds__(256) void sort_kernel(
    const int* __restrict__ top_e, const float* __restrict__ top_w,
    int* __restrict__ perm, float* __restrict__ wts, int* __restrict__ tokslot,
    int* __restrict__ tile_e, int* __restrict__ tile_m0, int* __restrict__ tile_cnt,
    int* __restrict__ n_tiles)
{
    __shared__ int hist[N_EXP][256];
    __shared__ int ebase[N_EXP];
    int tid = threadIdx.x, myexp = blockIdx.x;
    int c[N_EXP];
#pragma unroll
    for (int e = 0; e < N_EXP; ++e) c[e] = 0;
#pragma unroll 4
    for (int i = 0; i < 32; ++i) {
        int ee = top_e[tid * 32 + i];
#pragma unroll
        for (int e = 0; e < N_EXP; ++e) c[e] += (ee == e);
    }
#pragma unroll
    for (int e = 0; e < N_EXP; ++e) hist[e][tid] = c[e];
    __syncthreads();
    for (int s = 1; s < 256; s <<= 1) {
        int v[N_EXP];
#pragma unroll
        for (int e = 0; e < N_EXP; ++e) v[e] = (tid >= s) ? hist[e][tid - s] : 0;
        __syncthreads();
#pragma unroll
        for (int e = 0; e < N_EXP; ++e) hist[e][tid] += v[e];
        __syncthreads();
    }
    if (tid == 0) {
        int o = 0, nt = 0;
        for (int e = 0; e < N_EXP; ++e) {
            ebase[e] = o;
            int ne = hist[e][255];
            if (myexp == 0) {
                for (int m0 = 0; m0 < ne; m0 += BM) {
                    tile_e[nt]   = e;
                    tile_m0[nt]  = o + m0;
                    tile_cnt[nt] = (ne - m0 < BM) ? (ne - m0) : BM;
                    ++nt;
                }
            }
            o += ne;
        }
        if (myexp == 0) *n_tiles = nt;
    }
    __syncthreads();
    int base = ebase[myexp] + hist[myexp][tid] - c[myexp];
#pragma unroll 4
    for (int i = 0; i < 32; ++i) {
        int a = tid * 32 + i;
        if (top_e[a] == myexp) {
            perm[base]   = a >> 1;
            wts[base]    = top_w[a];
            tokslot[a]   = base;
            ++base;
        }
    }
}

// ---------------------------------------------------------------------------
// m97-structure grouped GEMM for gate+up (packed N=1024), 128x128 tile, BK=64,
// global_load_lds width-16 staging, XOR-swizzled LDS. 1-D grid, n-fastest
// decode (A-tile L3 reuse adjacent; B-tile + XCD affinity at stride 8).
// Epilogue: silu(gate)*up*combine_weight -> act (bf16).
// ---------------------------------------------------------------------------
__global__ __launch_bounds__(256, 3) void gateup_kernel(
    const __bf16* __restrict__ xb, const __bf16* __restrict__ Wcat,
    const int* __restrict__ perm, const float* __restrict__ wts,
    const int* __restrict__ tile_e, const int* __restrict__ tile_m0, const int* __restrict__ tile_cnt,
    const int* __restrict__ n_tiles, __bf16* __restrict__ act)
{
    int mt = blockIdx.x >> 3;
    if (mt >= *n_tiles) return;
    int e = tile_e[mt], m0 = tile_m0[mt], mcnt = tile_cnt[mt];
    int n0 = (blockIdx.x & 7) * BN;
    __shared__ __align__(16) __bf16 As[BM * BK];
    __shared__ __align__(16) __bf16 Bs[BN * BK];
    __shared__ int   rowtok[BM];
    __shared__ float roww[BM];
    int tid = threadIdx.x;
    if (tid < BM) {
        int slot = m0 + ((tid < mcnt) ? tid : 0);
        rowtok[tid] = perm[slot];
        roww[tid]   = wts[slot];
    }
    __syncthreads();
    int wave = tid >> 6, lane = tid & 63;
    int srow   = wave * 8 + (lane >> 3);
    int schunk = (((lane & 7) ^ ((lane >> 3) & 7))) * 8;
    const __bf16* We = Wcat + (size_t)e * (2 * F_DIM) * H_DIM;
    const __bf16* aptr[4];
    const __bf16* bptr[4];
#pragma unroll
    for (int j = 0; j < 4; ++j) {
        int r = j * 32 + srow;
        aptr[j] = xb + (size_t)rowtok[r] * H_DIM + schunk;
        bptr[j] = We + (size_t)(n0 + r) * H_DIM + schunk;
    }
    __bf16* aLds = As + wave * 512;
    __bf16* bLds = Bs + wave * 512;
    int wm = wave & 1, wn = wave >> 1;
    int quad = lane >> 4, l16 = lane & 15;
    f32x4 acc[4][4];
#pragma unroll
    for (int a = 0; a < 4; ++a)
#pragma unroll
        for (int b = 0; b < 4; ++b) acc[a][b] = (f32x4){0.f, 0.f, 0.f, 0.f};
    for (int k0 = 0; k0 < H_DIM; k0 += BK) {
#pragma unroll
        for (int j = 0; j < 4; ++j) {
            gl_lds16(aptr[j] + k0, aLds + j * 2048);
            gl_lds16(bptr[j] + k0, bLds + j * 2048);
        }
        __syncthreads();
#pragma unroll
        for (int s = 0; s < 2; ++s) {
            int sw = (((quad + s * 4) ^ (l16 & 7))) * 8;
            bf16x8 af[4], bf[4];
#pragma unroll
            for (int im = 0; im < 4; ++im)
                af[im] = *(const bf16x8*)&As[(wm * 64 + im * 16 + l16) * 64 + sw];
#pragma unroll
            for (int in = 0; in < 4; ++in)
                bf[in] = *(const bf16x8*)&Bs[(wn * 64 + in * 16 + l16) * 64 + sw];
#pragma unroll
            for (int im = 0; im < 4; ++im)
#pragma unroll
                for (int in = 0; in < 4; ++in)
                    acc[im][in] = MFMA16(af[im], bf[in], acc[im][in]);
        }
        __syncthreads();
    }
    int fbase = (n0 >> 1) + wn * 32;
#pragma unroll
    for (int im = 0; im < 4; ++im) {
#pragma unroll
        for (int ip = 0; ip < 2; ++ip) {
            f32x4 g = acc[im][ip * 2], u = acc[im][ip * 2 + 1];
            int fcol = fbase + ip * 16 + l16;
#pragma unroll
            for (int r = 0; r < 4; ++r) {
                int rl = wm * 64 + im * 16 + quad * 4 + r;
                if (rl < mcnt) {
                    float gv = g[r], uv = u[r];
                    float sg = gv / (1.f + __expf(-gv));
                    act[(size_t)(m0 + rl) * F_DIM + fcol] = (__bf16)(sg * uv * roww[rl]);
                }
            }
        }
    }
}

// ---------------------------------------------------------------------------
// m97-structure grouped down-proj: P[slot][h] = act[slot] @ Wd[e], bf16
// write-once stores (no atomics -- R5: 8.4M fp32 RMWs cost 42us).
// ---------------------------------------------------------------------------
__global__ __launch_bounds__(256, 3) void down_kernel(
    const __bf16* __restrict__ act, const __bf16* __restrict__ Wdt,
    const int* __restrict__ tile_e, const int* __restrict__ tile_m0, const int* __restrict__ tile_cnt,
    const int* __restrict__ n_tiles, __bf16* __restrict__ P)
{
    int mt = blockIdx.x >> 3;
    if (mt >= *n_tiles) return;
    int e = tile_e[mt], m0 = tile_m0[mt], mcnt = tile_cnt[mt];
    int n0 = (blockIdx.x & 7) * BN;
    __shared__ __align__(16) __bf16 As[BM * BK];
    __shared__ __align__(16) __bf16 Bs[BN * BK];
    int tid = threadIdx.x;
    int wave = tid >> 6, lane = tid & 63;
    int srow   = wave * 8 + (lane >> 3);
    int schunk = (((lane & 7) ^ ((lane >> 3) & 7))) * 8;
    const __bf16* Wd_e = Wdt + (size_t)e * H_DIM * F_DIM;
    const __bf16* aptr[4];
    const __bf16* bptr[4];
#pragma unroll
    for (int j = 0; j < 4; ++j) {
        int r = j * 32 + srow;
        int ar = m0 + ((r < mcnt) ? r : 0);
        aptr[j] = act  + (size_t)ar * F_DIM + schunk;
        bptr[j] = Wd_e + (size_t)(n0 + r) * F_DIM + schunk;
    }
    __bf16* aLds = As + wave * 512;
    __bf16* bLds = Bs + wave * 512;
    int wm = wave & 1, wn = wave >> 1;
    int quad = lane >> 4, l16 = lane & 15;
    f32x4 acc[4][4];
#pragma unroll
    for (int a = 0; a < 4; ++a)
#pragma unroll
        for (int b = 0; b < 4; ++b) acc[a][b] = (f32x4){0.f, 0.f, 0.f, 0.f};
    for (int k0 = 0; k0 < F_DIM; k0 += BK) {
#pragma unroll
        for (int j = 0; j < 4; ++j) {
            gl_lds16(aptr[j] + k0, aLds + j * 2048);
            gl_lds16(bptr[j] + k0, bLds + j * 2048);
        }
        __syncthreads();
#pragma unroll
        for (int s = 0; s < 2; ++s) {
            int sw = (((quad + s * 4) ^ (l16 & 7))) * 8;
            bf16x8 af[4], bf[4];
#pragma unroll
            for (int im = 0; im < 4; ++im)
                af[im] = *(const bf16x8*)&As[(wm * 64 + im * 16 + l16) * 64 + sw];
#pragma unroll
            for (int in = 0; in < 4; ++in)
                bf[in] = *(const bf16x8*)&Bs[(wn * 64 + in * 16 + l16) * 64 + sw];
#pragma unroll
            for (int im = 0; im < 4; ++im)
#pragma unroll
                for (int in = 0; in < 4; ++in)
                    acc[im][in] = MFMA16(af[im], bf[in], acc[im][in]);
        }
        __syncthreads();
    }
#pragma unroll
    for (int im = 0; im < 4; ++im) {
#pragma unroll
        for (int in = 0; in < 4; ++in) {
            int col = n0 + wn * 64 + in * 16 + l16;
#pragma unroll
            for (int r = 0; r < 4; ++r) {
                int rl = wm * 64 + im * 16 + quad * 4 + r;
                if (rl < mcnt)
                    P[(size_t)(m0 + rl) * H_DIM + col] = (__bf16)acc[im][in][r];
            }
        }
    }
}

// ---------------------------------------------------------------------------
// Combine: out[t] = P[slot1(t)] + P[slot2(t)] (fp32 accumulate). 1 wave/token,
// bf16x8 loads, f32x4 stores. Fully overwrites out (no memset needed).
// ---------------------------------------------------------------------------
__global__ __launch_bounds__(256) void combine_kernel(
    const __bf16* __restrict__ P, const int* __restrict__ tokslot,
    float* __restrict__ out)
{
    int wave = threadIdx.x >> 6, lane = threadIdx.x & 63;
    int t = blockIdx.x * 4 + wave;
    int s1 = tokslot[2 * t], s2 = tokslot[2 * t + 1];
    const bf16x8* p1 = (const bf16x8*)(P + (size_t)s1 * H_DIM);
    const bf16x8* p2 = (const bf16x8*)(P + (size_t)s2 * H_DIM);
    float* o = out + (size_t)t * H_DIM;
#pragma unroll
    for (int i = 0; i < 2; ++i) {
        int idx = i * 64 + lane;
        bf16x8 a = p1[idx], b = p2[idx];
        f32x4 lo, hi;
#pragma unroll
        for (int j = 0; j < 4; ++j) lo[j] = (float)a[j] + (float)b[j];
#pragma unroll
        for (int j = 0; j < 4; ++j) hi[j] = (float)a[4 + j] + (float)b[4 + j];
        *(f32x4*)(o + idx * 8)     = lo;
        *(f32x4*)(o + idx * 8 + 4) = hi;
    }
}

// ---------------------------------------------------------------------------
extern "C" void kernel_launch(void* const* d_in, const int* in_sizes, int n_in,
                              void* d_out, int out_size, void* d_ws, size_t ws_size,
                              hipStream_t stream)
{
    const float* x  = (const float*)d_in[0];
    const float* Wr = (const float*)d_in[1];
    const float* Wg = (const float*)d_in[2];
    const float* Wu = (const float*)d_in[3];
    const float* Wd = (const float*)d_in[4];
    float* out = (float*)d_out;

    char* ws = (char*)d_ws;
    size_t off = 0;
    auto carve = [&](size_t bytes) {
        char* p = ws + off;
        off = (off + bytes + 255) & ~(size_t)255;
        return p;
    };
    __bf16* xb   = (__bf16*)carve((size_t)T_TOK * H_DIM * 2);                 // 8 MB
    __bf16* Wcat = (__bf16*)carve((size_t)N_EXP * 2 * F_DIM * H_DIM * 2);     // 16 MB
    __bf16* Wdt  = (__bf16*)carve((size_t)N_EXP * H_DIM * F_DIM * 2);         // 8 MB
    __bf16* act  = (__bf16*)carve((size_t)N_ASSIGN * F_DIM * 2);              // 8 MB
    __bf16* P    = (__bf16*)carve((size_t)N_ASSIGN * H_DIM * 2);              // 16 MB
    int*   top_e = (int*)carve((size_t)T_TOK * 2 * sizeof(int));
    float* top_w = (float*)carve((size_t)T_TOK * 2 * sizeof(float));
    int*   perm  = (int*)carve((size_t)N_ASSIGN * sizeof(int));
    float* wts   = (float*)carve((size_t)N_ASSIGN * sizeof(float));
    int*  tokslot= (int*)carve((size_t)N_ASSIGN * sizeof(int));
    int*   tl_e  = (int*)carve(MAX_TILES * sizeof(int));
    int*   tl_m0 = (int*)carve(MAX_TILES * sizeof(int));
    int*   tl_cn = (int*)carve(MAX_TILES * sizeof(int));
    int*   n_til = (int*)carve(sizeof(int));

    prep_kernel<<<PREP_GRID, 256, 0, stream>>>(
        x, Wr, Wg, Wu, Wd, xb, top_e, top_w, Wcat, Wdt);
    sort_kernel<<<N_EXP, 256, 0, stream>>>(
        top_e, top_w, perm, wts, tokslot, tl_e, tl_m0, tl_cn, n_til);
    gateup_kernel<<<GRID_MT * 8, 256, 0, stream>>>(
        xb, Wcat, perm, wts, tl_e, tl_m0, tl_cn, n_til, act);
    down_kernel<<<GRID_MT * 8, 256, 0, stream>>>(
        act, Wdt, tl_e, tl_m0, tl_cn, n_til, P);
    combine_kernel<<<T_TOK / 4, 256, 0, stream>>>(P, tokslot, out);
}

// Round 11
// 191.114 us; speedup vs baseline: 3.4311x; 1.0613x over previous
//
#include <hip/hip_runtime.h>
#include <hip/hip_bf16.h>

// Problem constants (B=2,S=2048 -> T=4096 tokens), H=1024, F=512, E=8, top-2.
#define T_TOK    4096
#define H_DIM    1024
#define F_DIM    512
#define N_EXP    8
#define N_ASSIGN 8192          // T_TOK * 2
#define BM 128
#define BN 128
#define BK 64
#define MAX_TILES 80
#define GRID_MT   71           // worst-case sum_e ceil(Ne/128) = 64 + 7
#define TRU      3072          // transpose units: 2048 (Wg/Wu) + 1024 (Wd), 64x64 tiles

typedef __bf16 bf16x8 __attribute__((ext_vector_type(8)));
typedef float  f32x4  __attribute__((ext_vector_type(4)));

#define MFMA16(a, b, c) __builtin_amdgcn_mfma_f32_16x16x32_bf16((a), (b), (c), 0, 0, 0)

// Async global->LDS, 16B per lane. LDS dest = wave-uniform base + lane*16.
__device__ __forceinline__ void gl_lds16(const __bf16* g, __bf16* l) {
    __builtin_amdgcn_global_load_lds(
        (const __attribute__((address_space(1))) unsigned int*)g,
        (__attribute__((address_space(3))) unsigned int*)l,
        16, 0, 0);
}

// ---------------------------------------------------------------------------
// Transpose: fp32 -> bf16, K-contiguous layouts, 64x64 tiles, bf16x8 stores.
// (Split from R10's merged prep to regain per-kernel profiling visibility --
// merging phases measured as a no-op R6->R7.)
//   z<8 : Wg[h][f] -> Wcat[e][p_g(f)][h]   p_g(f) = (f>>4)*32 + (f&15)
//   z<16: Wu[h][f] -> Wcat[e][p_u(f)][h]   p_u(f) = p_g(f) + 16
//   else: Wd[f][h] -> Wdt [e][h][f]
// ---------------------------------------------------------------------------
__global__ __launch_bounds__(256) void transpose_kernel(
    const float* __restrict__ Wg, const float* __restrict__ Wu, const float* __restrict__ Wd,
    __bf16* __restrict__ Wcat, __bf16* __restrict__ Wdt)
{
    __shared__ float tile[64][65];     // 16.9 KB
    int b = blockIdx.x, tid = threadIdx.x;
    const float* src; int C, z, c0, r0;
    if (b < 2048) {                // Wg/Wu: R=1024, C=512 -> 16x8 tiles/z
        z = b >> 7; int rem = b & 127;
        c0 = (rem & 7) * 64; r0 = (rem >> 3) * 64;
        src = (z < 8) ? Wg + (size_t)z * H_DIM * F_DIM
                      : Wu + (size_t)(z - 8) * H_DIM * F_DIM;
        C = F_DIM;
    } else {                       // Wd: R=512, C=1024 -> 8x16 tiles/z
        int v = b - 2048; z = 16 + (v >> 7); int rem = v & 127;
        c0 = (rem & 15) * 64; r0 = (rem >> 4) * 64;
        src = Wd + (size_t)(z - 16) * F_DIM * H_DIM;
        C = H_DIM;
    }
    int fr = tid >> 4, f4 = tid & 15;          // 16 rows/pass, 16 float4/row
#pragma unroll
    for (int p = 0; p < 4; ++p) {
        int row = p * 16 + fr;
        float4 v = *(const float4*)(src + (size_t)(r0 + row) * C + c0 + f4 * 4);
        tile[row][f4 * 4 + 0] = v.x; tile[row][f4 * 4 + 1] = v.y;
        tile[row][f4 * 4 + 2] = v.z; tile[row][f4 * 4 + 3] = v.w;
    }
    __syncthreads();
    int j = tid & 7, cl = tid >> 3;            // chunk-of-8-rows, 32 cols/pass
#pragma unroll
    for (int p = 0; p < 2; ++p) {
        int c = cl + p * 32;
        bf16x8 v;
#pragma unroll
        for (int i = 0; i < 8; ++i) v[i] = (__bf16)tile[8 * j + i][c];
        if (z < 16) {
            int e = (z < 8) ? z : z - 8;
            int sel = (z < 8) ? 0 : 16;
            int f = c0 + c;
            int pp = ((f >> 4) << 5) + (f & 15) + sel;
            *(bf16x8*)&Wcat[(size_t)e * 2 * F_DIM * H_DIM + (size_t)pp * H_DIM + r0 + 8 * j] = v;
        } else {
            *(bf16x8*)&Wdt[(size_t)(z - 16) * H_DIM * F_DIM + (size_t)(c0 + c) * F_DIM + r0 + 8 * j] = v;
        }
    }
}

// ---------------------------------------------------------------------------
// Routing: 1 wave = 1 token, Wr staged in LDS as [e][h].
// R10 post-mortem: the old per-lane float4 Wr gather had 256-B lane stride ->
// every Wr load instruction touched 64 cache lines (~128 KB line traffic per
// wave, ~0.5 GB total, L1-thrashing). Now: Wr read coalesced ONCE per block
// into LDS; strips owned as h = s*64+lane so x loads are coalesced scalars
// and LDS reads hit bank=lane%32 (2-way = free, m136). No global atomics.
// ---------------------------------------------------------------------------
__global__ __launch_bounds__(256) void routing_kernel(
    const float* __restrict__ x, const float* __restrict__ Wr,
    __bf16* __restrict__ xb, int* __restrict__ top_e, float* __restrict__ top_w)
{
    __shared__ float WrS[N_EXP * H_DIM];   // [e][h], 32 KB
    int tid = threadIdx.x;
    for (int i = tid; i < N_EXP * H_DIM; i += 256) {
        int h = i >> 3, e = i & 7;         // global Wr is [h][e]
        WrS[e * H_DIM + h] = Wr[i];
    }
    __syncthreads();

    int wave = tid >> 6, lane = tid & 63;
    int t = blockIdx.x * 4 + wave;
    const float* xrow = x + (size_t)t * H_DIM;
    __bf16* xbrow = xb + (size_t)t * H_DIM;

    float part[N_EXP];
#pragma unroll
    for (int e = 0; e < N_EXP; ++e) part[e] = 0.f;
#pragma unroll 4
    for (int s = 0; s < 16; ++s) {
        int h = s * 64 + lane;
        float xs = xrow[h];
        xbrow[h] = (__bf16)xs;
#pragma unroll
        for (int e = 0; e < N_EXP; ++e) part[e] += xs * WrS[e * H_DIM + h];
    }
#pragma unroll
    for (int m = 1; m < 64; m <<= 1) {
#pragma unroll
        for (int e = 0; e < N_EXP; ++e) part[e] += __shfl_xor(part[e], m, 64);
    }
    if (lane == 0) {
        float v1 = -1e30f, v2 = -1e30f;
        int i1 = 0, i2 = 0;
#pragma unroll
        for (int e = 0; e < N_EXP; ++e) {
            float p = part[e];
            if (p > v1)      { v2 = v1; i2 = i1; v1 = p; i1 = e; }
            else if (p > v2) { v2 = p;  i2 = e; }
        }
        float w1 = 1.f / (1.f + __expf(v2 - v1));   // normalized top-2; softmax denom cancels
        top_e[t * 2]     = i1;  top_e[t * 2 + 1] = i2;
        top_w[t * 2]     = w1;  top_w[t * 2 + 1] = 1.f - w1;
    }
}

// ---------------------------------------------------------------------------
// sort (8 blocks): each block redundantly computes histogram + scan, scatters
// ONE expert at deterministic offsets; block 0 emits tile worklist. No atomics.
// ---------------------------------------------------------------------------
__global__ __launch_bounds__(256) void sort_kernel(
    const int* __restrict__ top_e, const float* __restrict__ top_w,
    int* __restrict__ perm, float* __restrict__ wts, int* __restrict__ tokslot,
    int* __restrict__ tile_e, int* __restrict__ tile_m0, int* __restrict__ tile_cnt,
    int* __restrict__ n_tiles)
{
    __shared__ int hist[N_EXP][256];
    __shared__ int ebase[N_EXP];
    int tid = threadIdx.x, myexp = blockIdx.x;
    int c[N_EXP];
#pragma unroll
    for (int e = 0; e < N_EXP; ++e) c[e] = 0;
#pragma unroll 4
    for (int i = 0; i < 32; ++i) {
        int ee = top_e[tid * 32 + i];
#pragma unroll
        for (int e = 0; e < N_EXP; ++e) c[e] += (ee == e);
    }
#pragma unroll
    for (int e = 0; e < N_EXP; ++e) hist[e][tid] = c[e];
    __syncthreads();
    for (int s = 1; s < 256; s <<= 1) {
        int v[N_EXP];
#pragma unroll
        for (int e = 0; e < N_EXP; ++e) v[e] = (tid >= s) ? hist[e][tid - s] : 0;
        __syncthreads();
#pragma unroll
        for (int e = 0; e < N_EXP; ++e) hist[e][tid] += v[e];
        __syncthreads();
    }
    if (tid == 0) {
        int o = 0, nt = 0;
        for (int e = 0; e < N_EXP; ++e) {
            ebase[e] = o;
            int ne = hist[e][255];
            if (myexp == 0) {
                for (int m0 = 0; m0 < ne; m0 += BM) {
                    tile_e[nt]   = e;
                    tile_m0[nt]  = o + m0;
                    tile_cnt[nt] = (ne - m0 < BM) ? (ne - m0) : BM;
                    ++nt;
                }
            }
            o += ne;
        }
        if (myexp == 0) *n_tiles = nt;
    }
    __syncthreads();
    int base = ebase[myexp] + hist[myexp][tid] - c[myexp];
#pragma unroll 4
    for (int i = 0; i < 32; ++i) {
        int a = tid * 32 + i;
        if (top_e[a] == myexp) {
            perm[base]   = a >> 1;
            wts[base]    = top_w[a];
            tokslot[a]   = base;
            ++base;
        }
    }
}

// ---------------------------------------------------------------------------
// m97-structure grouped GEMM for gate+up (packed N=1024), 128x128 tile, BK=64,
// global_load_lds width-16 staging, XOR-swizzled LDS. 1-D grid, n-fastest
// decode (A-tile L3 reuse adjacent; B-tile + XCD affinity at stride 8).
// Epilogue: silu(gate)*up*combine_weight -> act (bf16).
// ---------------------------------------------------------------------------
__global__ __launch_bounds__(256, 3) void gateup_kernel(
    const __bf16* __restrict__ xb, const __bf16* __restrict__ Wcat,
    const int* __restrict__ perm, const float* __restrict__ wts,
    const int* __restrict__ tile_e, const int* __restrict__ tile_m0, const int* __restrict__ tile_cnt,
    const int* __restrict__ n_tiles, __bf16* __restrict__ act)
{
    int mt = blockIdx.x >> 3;
    if (mt >= *n_tiles) return;
    int e = tile_e[mt], m0 = tile_m0[mt], mcnt = tile_cnt[mt];
    int n0 = (blockIdx.x & 7) * BN;
    __shared__ __align__(16) __bf16 As[BM * BK];
    __shared__ __align__(16) __bf16 Bs[BN * BK];
    __shared__ int   rowtok[BM];
    __shared__ float roww[BM];
    int tid = threadIdx.x;
    if (tid < BM) {
        int slot = m0 + ((tid < mcnt) ? tid : 0);
        rowtok[tid] = perm[slot];
        roww[tid]   = wts[slot];
    }
    __syncthreads();
    int wave = tid >> 6, lane = tid & 63;
    int srow   = wave * 8 + (lane >> 3);
    int schunk = (((lane & 7) ^ ((lane >> 3) & 7))) * 8;
    const __bf16* We = Wcat + (size_t)e * (2 * F_DIM) * H_DIM;
    const __bf16* aptr[4];
    const __bf16* bptr[4];
#pragma unroll
    for (int j = 0; j < 4; ++j) {
        int r = j * 32 + srow;
        aptr[j] = xb + (size_t)rowtok[r] * H_DIM + schunk;
        bptr[j] = We + (size_t)(n0 + r) * H_DIM + schunk;
    }
    __bf16* aLds = As + wave * 512;
    __bf16* bLds = Bs + wave * 512;
    int wm = wave & 1, wn = wave >> 1;
    int quad = lane >> 4, l16 = lane & 15;
    f32x4 acc[4][4];
#pragma unroll
    for (int a = 0; a < 4; ++a)
#pragma unroll
        for (int b = 0; b < 4; ++b) acc[a][b] = (f32x4){0.f, 0.f, 0.f, 0.f};
    for (int k0 = 0; k0 < H_DIM; k0 += BK) {
#pragma unroll
        for (int j = 0; j < 4; ++j) {
            gl_lds16(aptr[j] + k0, aLds + j * 2048);
            gl_lds16(bptr[j] + k0, bLds + j * 2048);
        }
        __syncthreads();
#pragma unroll
        for (int s = 0; s < 2; ++s) {
            int sw = (((quad + s * 4) ^ (l16 & 7))) * 8;
            bf16x8 af[4], bf[4];
#pragma unroll
            for (int im = 0; im < 4; ++im)
                af[im] = *(const bf16x8*)&As[(wm * 64 + im * 16 + l16) * 64 + sw];
#pragma unroll
            for (int in = 0; in < 4; ++in)
                bf[in] = *(const bf16x8*)&Bs[(wn * 64 + in * 16 + l16) * 64 + sw];
#pragma unroll
            for (int im = 0; im < 4; ++im)
#pragma unroll
                for (int in = 0; in < 4; ++in)
                    acc[im][in] = MFMA16(af[im], bf[in], acc[im][in]);
        }
        __syncthreads();
    }
    int fbase = (n0 >> 1) + wn * 32;
#pragma unroll
    for (int im = 0; im < 4; ++im) {
#pragma unroll
        for (int ip = 0; ip < 2; ++ip) {
            f32x4 g = acc[im][ip * 2], u = acc[im][ip * 2 + 1];
            int fcol = fbase + ip * 16 + l16;
#pragma unroll
            for (int r = 0; r < 4; ++r) {
                int rl = wm * 64 + im * 16 + quad * 4 + r;
                if (rl < mcnt) {
                    float gv = g[r], uv = u[r];
                    float sg = gv / (1.f + __expf(-gv));
                    act[(size_t)(m0 + rl) * F_DIM + fcol] = (__bf16)(sg * uv * roww[rl]);
                }
            }
        }
    }
}

// ---------------------------------------------------------------------------
// m97-structure grouped down-proj: P[slot][h] = act[slot] @ Wd[e], bf16
// write-once stores (no atomics -- R5: 8.4M fp32 RMWs cost 42us).
// ---------------------------------------------------------------------------
__global__ __launch_bounds__(256, 3) void down_kernel(
    const __bf16* __restrict__ act, const __bf16* __restrict__ Wdt,
    const int* __restrict__ tile_e, const int* __restrict__ tile_m0, const int* __restrict__ tile_cnt,
    const int* __restrict__ n_tiles, __bf16* __restrict__ P)
{
    int mt = blockIdx.x >> 3;
    if (mt >= *n_tiles) return;
    int e = tile_e[mt], m0 = tile_m0[mt], mcnt = tile_cnt[mt];
    int n0 = (blockIdx.x & 7) * BN;
    __shared__ __align__(16) __bf16 As[BM * BK];
    __shared__ __align__(16) __bf16 Bs[BN * BK];
    int tid = threadIdx.x;
    int wave = tid >> 6, lane = tid & 63;
    int srow   = wave * 8 + (lane >> 3);
    int schunk = (((lane & 7) ^ ((lane >> 3) & 7))) * 8;
    const __bf16* Wd_e = Wdt + (size_t)e * H_DIM * F_DIM;
    const __bf16* aptr[4];
    const __bf16* bptr[4];
#pragma unroll
    for (int j = 0; j < 4; ++j) {
        int r = j * 32 + srow;
        int ar = m0 + ((r < mcnt) ? r : 0);
        aptr[j] = act  + (size_t)ar * F_DIM + schunk;
        bptr[j] = Wd_e + (size_t)(n0 + r) * F_DIM + schunk;
    }
    __bf16* aLds = As + wave * 512;
    __bf16* bLds = Bs + wave * 512;
    int wm = wave & 1, wn = wave >> 1;
    int quad = lane >> 4, l16 = lane & 15;
    f32x4 acc[4][4];
#pragma unroll
    for (int a = 0; a < 4; ++a)
#pragma unroll
        for (int b = 0; b < 4; ++b) acc[a][b] = (f32x4){0.f, 0.f, 0.f, 0.f};
    for (int k0 = 0; k0 < F_DIM; k0 += BK) {
#pragma unroll
        for (int j = 0; j < 4; ++j) {
            gl_lds16(aptr[j] + k0, aLds + j * 2048);
            gl_lds16(bptr[j] + k0, bLds + j * 2048);
        }
        __syncthreads();
#pragma unroll
        for (int s = 0; s < 2; ++s) {
            int sw = (((quad + s * 4) ^ (l16 & 7))) * 8;
            bf16x8 af[4], bf[4];
#pragma unroll
            for (int im = 0; im < 4; ++im)
                af[im] = *(const bf16x8*)&As[(wm * 64 + im * 16 + l16) * 64 + sw];
#pragma unroll
            for (int in = 0; in < 4; ++in)
                bf[in] = *(const bf16x8*)&Bs[(wn * 64 + in * 16 + l16) * 64 + sw];
#pragma unroll
            for (int im = 0; im < 4; ++im)
#pragma unroll
                for (int in = 0; in < 4; ++in)
                    acc[im][in] = MFMA16(af[im], bf[in], acc[im][in]);
        }
        __syncthreads();
    }
#pragma unroll
    for (int im = 0; im < 4; ++im) {
#pragma unroll
        for (int in = 0; in < 4; ++in) {
            int col = n0 + wn * 64 + in * 16 + l16;
#pragma unroll
            for (int r = 0; r < 4; ++r) {
                int rl = wm * 64 + im * 16 + quad * 4 + r;
                if (rl < mcnt)
                    P[(size_t)(m0 + rl) * H_DIM + col] = (__bf16)acc[im][in][r];
            }
        }
    }
}

// ---------------------------------------------------------------------------
// Combine: out[t] = P[slot1(t)] + P[slot2(t)] (fp32 accumulate). 1 wave/token,
// bf16x8 loads, f32x4 stores. Fully overwrites out (no memset needed).
// ---------------------------------------------------------------------------
__global__ __launch_bounds__(256) void combine_kernel(
    const __bf16* __restrict__ P, const int* __restrict__ tokslot,
    float* __restrict__ out)
{
    int wave = threadIdx.x >> 6, lane = threadIdx.x & 63;
    int t = blockIdx.x * 4 + wave;
    int s1 = tokslot[2 * t], s2 = tokslot[2 * t + 1];
    const bf16x8* p1 = (const bf16x8*)(P + (size_t)s1 * H_DIM);
    const bf16x8* p2 = (const bf16x8*)(P + (size_t)s2 * H_DIM);
    float* o = out + (size_t)t * H_DIM;
#pragma unroll
    for (int i = 0; i < 2; ++i) {
        int idx = i * 64 + lane;
        bf16x8 a = p1[idx], b = p2[idx];
        f32x4 lo, hi;
#pragma unroll
        for (int j = 0; j < 4; ++j) lo[j] = (float)a[j] + (float)b[j];
#pragma unroll
        for (int j = 0; j < 4; ++j) hi[j] = (float)a[4 + j] + (float)b[4 + j];
        *(f32x4*)(o + idx * 8)     = lo;
        *(f32x4*)(o + idx * 8 + 4) = hi;
    }
}

// ---------------------------------------------------------------------------
extern "C" void kernel_launch(void* const* d_in, const int* in_sizes, int n_in,
                              void* d_out, int out_size, void* d_ws, size_t ws_size,
                              hipStream_t stream)
{
    const float* x  = (const float*)d_in[0];
    const float* Wr = (const float*)d_in[1];
    const float* Wg = (const float*)d_in[2];
    const float* Wu = (const float*)d_in[3];
    const float* Wd = (const float*)d_in[4];
    float* out = (float*)d_out;

    char* ws = (char*)d_ws;
    size_t off = 0;
    auto carve = [&](size_t bytes) {
        char* p = ws + off;
        off = (off + bytes + 255) & ~(size_t)255;
        return p;
    };
    __bf16* xb   = (__bf16*)carve((size_t)T_TOK * H_DIM * 2);                 // 8 MB
    __bf16* Wcat = (__bf16*)carve((size_t)N_EXP * 2 * F_DIM * H_DIM * 2);     // 16 MB
    __bf16* Wdt  = (__bf16*)carve((size_t)N_EXP * H_DIM * F_DIM * 2);         // 8 MB
    __bf16* act  = (__bf16*)carve((size_t)N_ASSIGN * F_DIM * 2);              // 8 MB
    __bf16* P    = (__bf16*)carve((size_t)N_ASSIGN * H_DIM * 2);              // 16 MB
    int*   top_e = (int*)carve((size_t)T_TOK * 2 * sizeof(int));
    float* top_w = (float*)carve((size_t)T_TOK * 2 * sizeof(float));
    int*   perm  = (int*)carve((size_t)N_ASSIGN * sizeof(int));
    float* wts   = (float*)carve((size_t)N_ASSIGN * sizeof(float));
    int*  tokslot= (int*)carve((size_t)N_ASSIGN * sizeof(int));
    int*   tl_e  = (int*)carve(MAX_TILES * sizeof(int));
    int*   tl_m0 = (int*)carve(MAX_TILES * sizeof(int));
    int*   tl_cn = (int*)carve(MAX_TILES * sizeof(int));
    int*   n_til = (int*)carve(sizeof(int));

    transpose_kernel<<<TRU, 256, 0, stream>>>(Wg, Wu, Wd, Wcat, Wdt);
    routing_kernel<<<T_TOK / 4, 256, 0, stream>>>(x, Wr, xb, top_e, top_w);
    sort_kernel<<<N_EXP, 256, 0, stream>>>(
        top_e, top_w, perm, wts, tokslot, tl_e, tl_m0, tl_cn, n_til);
    gateup_kernel<<<GRID_MT * 8, 256, 0, stream>>>(
        xb, Wcat, perm, wts, tl_e, tl_m0, tl_cn, n_til, act);
    down_kernel<<<GRID_MT * 8, 256, 0, stream>>>(
        act, Wdt, tl_e, tl_m0, tl_cn, n_til, P);
    combine_kernel<<<T_TOK / 4, 256, 0, stream>>>(P, tokslot, out);
}